// Round 12
// baseline (178.746 us; speedup 1.0000x reference)
//
#include <hip/hip_runtime.h>

// ---------------------------------------------------------------------------
// Attention_52424370815683: B=2, S=2048, D=1024, H=16, hd=64. f32 I/O.
//   k0: convert x|qkv_w|proj_w f32 -> bf16, 2048-block grid-stride x4
//   k1: qkv GEMM, 128x128 BK=32 dbuf 2-phase, 512 thr, 3 blocks/CU.
//       **XCD-rectangle remap: each XCD owns 12(bx) x 8(by) -> 5 MB panel
//       footprint (was 8.75 MB: X thrashed L2, re-streamed from L3).**
//   k2: flash attention (r10/r11, banked): 512 thr / 8 waves = 4 qtiles x
//       2 keyhalves, LDS K/V dbuf per half, 32x32 swapped-QK, in-register
//       P via cvt_pk + permlane swap, split-K LDS merge. ~47 us.
//   k3: proj GEMM, 128x64 tile, 512 thr / 8 waves.
//       **XCD-rectangle remap: 8(bx) x 8(by) -> 3 MB < 4 MB L2-resident.**
// ---------------------------------------------------------------------------

typedef __bf16 bf16_8 __attribute__((ext_vector_type(8)));
typedef __bf16 bf16_4 __attribute__((ext_vector_type(4)));
typedef __bf16 bf16_2 __attribute__((ext_vector_type(2)));
typedef float floatx2 __attribute__((ext_vector_type(2)));
typedef float floatx4 __attribute__((ext_vector_type(4)));
typedef float floatx16 __attribute__((ext_vector_type(16)));
typedef unsigned uintx4 __attribute__((ext_vector_type(4)));

#define MFMA16 __builtin_amdgcn_mfma_f32_16x16x32_bf16
#define MFMA32 __builtin_amdgcn_mfma_f32_32x32x16_bf16
#define CSCALE 0.1803368801111204f   // hd^-0.5 * log2(e)
#define EXP2R  __builtin_amdgcn_exp2f   // bare v_exp_f32 (no OCML denorm fixup)

__device__ __forceinline__ void gld16(const __bf16* g, __bf16* l) {
    __builtin_amdgcn_global_load_lds(
        (const __attribute__((address_space(1))) void*)g,
        (__attribute__((address_space(3))) void*)l, 16, 0, 0);
}

// single-instruction packed f32->bf16 (RNE), lo = a, hi = b
__device__ __forceinline__ unsigned cvtpk_bf16(float a, float b) {
    unsigned d;
    __asm__("v_cvt_pk_bf16_f32 %0, %1, %2" : "=v"(d) : "v"(a), "v"(b));
    return d;
}

// v_permlane32_swap_b32: after the op, a = {a_lo, b_lo}, b = {a_hi, b_hi}
// volatile: the r2/r6/r10 (passing) form -- pinned in program order.
__device__ __forceinline__ void pl32swap(unsigned& a, unsigned& b) {
    __asm__ __volatile__("v_permlane32_swap_b32 %0, %1" : "+v"(a), "+v"(b));
}

// ---------------------------------------------------------------------------
// Kernel 0: merged f32 -> bf16 convert for x (1M f4), qkv_w (768K), proj_w
// (256K). 2048 blocks x 256 thr, grid-stride x4 (2M float4 total).
// ---------------------------------------------------------------------------
__global__ __launch_bounds__(256) void cvt_all(
    const float* __restrict__ x, const float* __restrict__ w1,
    const float* __restrict__ w2,
    __bf16* __restrict__ xb, __bf16* __restrict__ w1b, __bf16* __restrict__ w2b)
{
    const int base = blockIdx.x * 256 + threadIdx.x;
#pragma unroll
    for (int g = 0; g < 4; ++g) {
        const int i = base + g * 524288;              // float4 index
        const float* src; __bf16* dst; int off;
        if (i < (1 << 20))                  { src = x;  dst = xb;  off = i; }
        else if (i < (1 << 20) + 786432)    { src = w1; dst = w1b; off = i - (1 << 20); }
        else                                { src = w2; dst = w2b; off = i - (1 << 20) - 786432; }
        float4 v = ((const float4*)src)[off];
        bf16_4 o;
        o[0] = (__bf16)v.x; o[1] = (__bf16)v.y; o[2] = (__bf16)v.z; o[3] = (__bf16)v.w;
        ((bf16_4*)dst)[off] = o;
    }
}

// ---------------------------------------------------------------------------
// Kernel 1: QKV GEMM. M=4096, N=3072, K=1024. grid (24,32) = 768 blocks,
// 512 threads, 8 waves (2M x 4N), 128x128 tile, BK=32, dbuf LDS (32 KB ->
// 3 blocks/CU, all 768 resident). XCD-rectangle remap: XCD x owns bx in
// [(x&1)*12,+12) x by in [(x>>1)*8,+8): per-XCD panels = W 3 MB + X 2 MB
// = 5 MB (old bx%8 mapping: W 0.75 + X 8 = 8.75 MB -> L2 thrash, X
// re-streamed from L3 ~8x). 2-phase: stage(k+1)->compute(k)->vmcnt+barrier.
// Epilogues: q/k -> [b,h,s,d] (k scaled by CSCALE), v -> vT[b,h,d,s].
// ---------------------------------------------------------------------------
__global__ __launch_bounds__(512) void qkv_gemm(
    const __bf16* __restrict__ X, const __bf16* __restrict__ W,
    __bf16* __restrict__ q_ws, __bf16* __restrict__ k_ws, __bf16* __restrict__ vt_ws)
{
    __shared__ __align__(16) __bf16 S[2][2][128 * 32];  // [buf][A/B] 32 KB

    const int tid = threadIdx.x, lane = tid & 63, wv = tid >> 6;   // wv 0..7
    const int quad = lane >> 4, l15 = lane & 15;
    const int wm = (wv >> 2) * 64, wn = (wv & 3) * 32;  // 2 x 4 wave grid

    // XCD-rectangle remap (bijective over 768): XCD = linear%8 owns a
    // 12(bx) x 8(by) rectangle of the (24,32) tile grid.
    const int linear = blockIdx.x + 24 * blockIdx.y;
    const int xcd = linear & 7, rr = linear >> 3;       // rr 0..95
    const int bx = (xcd & 1) * 12 + rr % 12;
    const int by = (xcd >> 1) * 8 + rr / 12;
    const int m0 = by * 128, n0 = bx * 128;
    const int c = n0 >> 10;                         // 0=q 1=k 2=v (block-uniform)

    // A/B row bases (both K-major, stride 1024). c<2: swapped (rows=feature).
    const __bf16* Abase;
    const __bf16* Bbase;
    if (c == 2) { Abase = X + (size_t)m0 * 1024; Bbase = W + (size_t)n0 * 1024; }
    else        { Abase = W + (size_t)n0 * 1024; Bbase = X + (size_t)m0 * 1024; }

    // staging: 128 rows x 4 chunks(8 elem) = 512 chunks = 1/thread/operand.
    // physical slot skc of row srow holds logical chunk skc^(srow&3).
    const int srow = tid >> 2, skc = tid & 3;       // srow 0..127
    const int ssw  = ((skc ^ (srow & 3)) * 8);

#define QKV_STAGE(buf, k0)                                                     \
    {                                                                          \
        gld16(Abase + srow * 1024 + (k0) + ssw, &S[buf][0][tid * 8]);          \
        gld16(Bbase + srow * 1024 + (k0) + ssw, &S[buf][1][tid * 8]);          \
    }

    floatx4 acc[4][2] = {};
    QKV_STAGE(0, 0)
    __syncthreads();

#pragma unroll 1
    for (int kk = 0; kk < 32; ++kk) {
        const int cur = kk & 1;
        if (kk < 31) QKV_STAGE(cur ^ 1, (kk + 1) * 32)

        const __bf16* As = S[cur][0];
        const __bf16* Bs = S[cur][1];
        bf16_8 af[4], bf[2];
#pragma unroll
        for (int mt = 0; mt < 4; ++mt) {
            int r = wm + mt * 16 + l15;
            af[mt] = *(const bf16_8*)&As[r * 32 + ((quad ^ (r & 3)) * 8)];
        }
#pragma unroll
        for (int nt = 0; nt < 2; ++nt) {
            int r = wn + nt * 16 + l15;
            bf[nt] = *(const bf16_8*)&Bs[r * 32 + ((quad ^ (r & 3)) * 8)];
        }
#pragma unroll
        for (int mt = 0; mt < 4; ++mt)
#pragma unroll
            for (int nt = 0; nt < 2; ++nt)
                acc[mt][nt] = MFMA16(af[mt], bf[nt], acc[mt][nt], 0, 0, 0);

        if (kk < 31) {
            __asm__ __volatile__("s_waitcnt vmcnt(0)" ::: "memory");
            __syncthreads();
        }
    }

    if (c == 2) {
        // V: D rows = token, cols = feature. Pack 4 consecutive tokens -> vT.
#pragma unroll
        for (int mt = 0; mt < 4; ++mt) {
            const int mbase = m0 + wm + mt * 16 + quad * 4;   // token, 4-aligned
            const int b = mbase >> 11, s = mbase & 2047;
#pragma unroll
            for (int nt = 0; nt < 2; ++nt) {
                const int n = n0 + wn + nt * 16 + l15;
                const int h = (n >> 6) & 15, d = n & 63;
                bf16_4 pk;
#pragma unroll
                for (int r = 0; r < 4; ++r) pk[r] = (__bf16)acc[mt][nt][r];
                *(bf16_4*)&vt_ws[((size_t)(b * 16 + h) * 64 + d) * 2048 + s] = pk;
            }
        }
    } else {
        // q/k: swapped -> D rows = feature, cols = token. d-contiguous stores.
        __bf16* dst = (c == 0) ? q_ws : k_ws;
        const float scale = (c == 1) ? CSCALE : 1.0f;
#pragma unroll
        for (int mt = 0; mt < 4; ++mt) {
            const int nn = n0 + wm + mt * 16 + quad * 4;      // feature, 4-aligned
            const int h = (nn >> 6) & 15, d0 = nn & 63;
#pragma unroll
            for (int nt = 0; nt < 2; ++nt) {
                const int token = m0 + wn + nt * 16 + l15;
                const int b = token >> 11, skey = token & 2047;
                bf16_4 pk;
#pragma unroll
                for (int r = 0; r < 4; ++r) pk[r] = (__bf16)(acc[mt][nt][r] * scale);
                *(bf16_4*)&dst[((size_t)(b * 16 + h) * 2048 + skey) * 64 + d0] = pk;
            }
        }
    }
#undef QKV_STAGE
}

// ---------------------------------------------------------------------------
// Kernel 2: flash attention (r10/r11, banked). grid (16 qt, 32 bh) remapped
// (linear%8 = XCD owns 4 bh). 512 thr / 8 waves: qtile = w&3, keyhalf =
// w>>2. Each wave: 32 q x 1024 keys = 16 tiles from its half's dbuf LDS
// K/V (staged by the half's 256 threads, shared by 4 waves -> VGPR 64 ->
// high occupancy). Per tile: QK (8 MFMA32, fzero C-in), fused per-s
// {exp/pack -> permlane swap -> 2 PV MFMA}. Split-K merge via LDS overlay.
// ---------------------------------------------------------------------------
__global__ __launch_bounds__(512, 4) void attn_kernel(
    const __bf16* __restrict__ q_ws, const __bf16* __restrict__ k_ws,
    const __bf16* __restrict__ vt_ws, __bf16* __restrict__ attn_ws)
{
    __shared__ __align__(16) __bf16 Ks [2][2][64 * 64];   // [half][buf] 32 KB
    __shared__ __align__(16) __bf16 Vts[2][2][64 * 64];   // [half][buf] 32 KB

    const int tid = threadIdx.x, lane = tid & 63, w = tid >> 6;   // w 0..7
    const int l31 = lane & 31, hi = lane >> 5;
    const int qtile = w & 3, keyhalf = w >> 2;
    const int htid = tid & 255;                     // thread within half

    // XCD remap: linear = bx + 16*by in [0,512); XCD = linear%8 owns 4 bh.
    const int linear = blockIdx.x + (blockIdx.y << 4);
    const int r = linear >> 3;                      // 0..63
    const int bh = ((linear & 7) << 2) + (r & 3);
    const int qt = r >> 2;                          // 0..15
    const int q0 = qt * 128 + qtile * 32;

    const __bf16* __restrict__ qp  = q_ws  + (size_t)bh * (2048 * 64);
    const __bf16* __restrict__ kp  = k_ws  + (size_t)bh * (2048 * 64);
    const __bf16* __restrict__ vtp = vt_ws + (size_t)bh * (64 * 2048);
    const int koff = keyhalf * 1024;                // this half's key base

    // staging: loop-invariant per-lane bases
    const int srow = htid >> 3, skc = htid & 7;     // srow 0..31
    const int sw   = (skc ^ (srow & 7)) * 8;
    const __bf16* kb0 = kp  + (size_t)(koff + srow) * 64 + sw;
    const __bf16* kb1 = kp  + (size_t)(koff + srow + 32) * 64 + sw;
    const __bf16* vb0 = vtp + (size_t)srow * 2048 + koff + sw;
    const __bf16* vb1 = vtp + (size_t)(srow + 32) * 2048 + koff + sw;
    const int ldsoff = htid * 8;                    // wave-uniform + lane*16B

    // Q B-frags (4 k-steps of 16), held in registers all loop
    bf16_8 qf[4];
    {
        const int qrow = q0 + l31;
#pragma unroll
        for (int s = 0; s < 4; ++s)
            qf[s] = *(const bf16_8*)&qp[qrow * 64 + s * 16 + hi * 8];
    }

    floatx16 oacc[2] = {};                  // [d-tile] O^T accumulators
    floatx2 ls2[4] = {};                    // packed row-sum partials
    const floatx16 fzero = {};              // persistent zero C-in (hoisted)

    // prologue: stage tile 0 into buf 0
    gld16(kb0, &Ks [keyhalf][0][ldsoff]);
    gld16(kb1, &Ks [keyhalf][0][ldsoff + 2048]);
    gld16(vb0, &Vts[keyhalf][0][ldsoff]);
    gld16(vb1, &Vts[keyhalf][0][ldsoff + 2048]);
    __syncthreads();                        // drains vmcnt(0): buf0 ready

#pragma unroll 1
    for (int kt = 0; kt < 16; ++kt) {
        const int cur = kt & 1;
        // ---- issue next tile's stage FIRST (hidden under compute)
        if (kt < 15) {
            const int ko = (kt + 1) * 64;
            gld16(kb0 + ko * 64, &Ks [keyhalf][cur ^ 1][ldsoff]);
            gld16(kb1 + ko * 64, &Ks [keyhalf][cur ^ 1][ldsoff + 2048]);
            gld16(vb0 + ko,      &Vts[keyhalf][cur ^ 1][ldsoff]);
            gld16(vb1 + ko,      &Vts[keyhalf][cur ^ 1][ldsoff + 2048]);
        }
        const __bf16* Kb = Ks [keyhalf][cur];
        const __bf16* Vb = Vts[keyhalf][cur];

        // ---- S^T[64 key][32 q]: 2 key-subtiles x 4 k-steps
        floatx16 sacc[2];
        __builtin_amdgcn_s_setprio(1);
        {
            const int kc0 = hi;
            const int r0 = l31, r1 = 32 + l31;
            bf16_8 kf0 = *(const bf16_8*)&Kb[r0 * 64 + ((kc0 ^ (r0 & 7)) * 8)];
            bf16_8 kf1 = *(const bf16_8*)&Kb[r1 * 64 + ((kc0 ^ (r1 & 7)) * 8)];
            sacc[0] = MFMA32(kf0, qf[0], fzero, 0, 0, 0);
            sacc[1] = MFMA32(kf1, qf[0], fzero, 0, 0, 0);
        }
#pragma unroll
        for (int s = 1; s < 4; ++s) {
            const int kc = s * 2 + hi;
#pragma unroll
            for (int t = 0; t < 2; ++t) {
                const int row = t * 32 + l31;
                bf16_8 kf = *(const bf16_8*)&Kb[row * 64 + ((kc ^ (row & 7)) * 8)];
                sacc[t] = MFMA32(kf, qf[s], sacc[t], 0, 0, 0);
            }
        }
        __builtin_amdgcn_s_setprio(0);

        // ---- fused per-s: exp/pack quarter -> permlane swap -> 2 PV MFMAs
#pragma unroll
        for (int s = 0; s < 4; ++s) {
            const int t = s >> 1, b2 = (s & 1) * 2;
            unsigned Dw[4];                 // [jrel*2+e], j = b2+jrel
#pragma unroll
            for (int jr = 0; jr < 2; ++jr)
#pragma unroll
                for (int e = 0; e < 2; ++e) {
                    const int j = b2 + jr;
                    float pa = EXP2R(sacc[t][j * 4 + e * 2]);
                    float pb = EXP2R(sacc[t][j * 4 + e * 2 + 1]);
                    floatx2 p2; p2[0] = pa; p2[1] = pb;
                    ls2[t * 2 + e] += p2;        // v_pk_add_f32
                    Dw[jr * 2 + e] = cvtpk_bf16(pa, pb);
                }
            unsigned x0 = Dw[0], y0 = Dw[2];
            unsigned x1 = Dw[1], y1 = Dw[3];
            pl32swap(x0, y0);
            pl32swap(x1, y1);
            uintx4 uu; uu[0] = x0; uu[1] = x1; uu[2] = y0; uu[3] = y1;
            const bf16_8 pf = __builtin_bit_cast(bf16_8, uu);
            const int kc = s * 2 + hi;
            __builtin_amdgcn_s_setprio(1);
#pragma unroll
            for (int dt = 0; dt < 2; ++dt) {
                const int drow = dt * 32 + l31;
                bf16_8 vf = *(const bf16_8*)&Vb[drow * 64 + ((kc ^ (drow & 7)) * 8)];
                oacc[dt] = MFMA32(vf, pf, oacc[dt], 0, 0, 0);
            }
            __builtin_amdgcn_s_setprio(0);
        }

        // ---- single barrier per tile: stage loads drained + buf reads done
        if (kt < 15) {
            __asm__ __volatile__("s_waitcnt vmcnt(0)" ::: "memory");
            __syncthreads();
        }
    }

    // ---- this wave's row-sums over its 1024 keys (combine hi halves)
    const floatx2 lv = (ls2[0] + ls2[1]) + (ls2[2] + ls2[3]);
    const float lsum = lv[0] + lv[1];
    const float lw = lsum + __shfl_xor(lsum, 32, 64);

    // ---- split-K merge (LDS overlay on K/V buffers; all reads done)
    __syncthreads();
    floatx4* comb  = (floatx4*)&Ks[0][0][0];    // [qtile][8][64] = 32 KB exact
    float*   lcomb = (float*)&Vts[0][0][0];     // [qtile][64] = 1 KB

    if (keyhalf == 1) {
#pragma unroll
        for (int dt = 0; dt < 2; ++dt)
#pragma unroll
            for (int g = 0; g < 4; ++g) {
                floatx4 v4;
#pragma unroll
                for (int r4 = 0; r4 < 4; ++r4) v4[r4] = oacc[dt][g * 4 + r4];
                comb[((qtile * 8 + dt * 4 + g) << 6) + lane] = v4;
            }
        lcomb[(qtile << 6) + lane] = lw;
    }
    __syncthreads();
    if (keyhalf == 0) {
        // oacc C32 layout: col = q = lane&31, row d = (r&3)+8*(r>>2)+4*hi.
        const int b = bh >> 4, h = bh & 15;
        const float inv_l = 1.0f / (lw + lcomb[(qtile << 6) + lane]);
        const int token = b * 2048 + q0 + l31;
#pragma unroll
        for (int dt = 0; dt < 2; ++dt)
#pragma unroll
            for (int g = 0; g < 4; ++g) {
                const floatx4 v2 = comb[((qtile * 8 + dt * 4 + g) << 6) + lane];
                bf16_4 ok;
#pragma unroll
                for (int r4 = 0; r4 < 4; ++r4)
                    ok[r4] = (__bf16)((oacc[dt][g * 4 + r4] + v2[r4]) * inv_l);
                *(bf16_4*)&attn_ws[(size_t)token * 1024 + h * 64 + dt * 32 + g * 8 + hi * 4] = ok;
            }
    }
}

// ---------------------------------------------------------------------------
// Kernel 3: proj GEMM + bias -> f32 out. M=4096, N=1024, K=1024.
// 128x64 tiles, grid (16,32) = 512 blocks, 512 threads / 8 waves (4Mx2N).
// XCD-rectangle remap: XCD x owns bx in [(x&1)*8,+8) x by in [(x>>1)*8,+8):
// per-XCD panels = W 1 MB + A 2 MB = 3 MB < 4 MB L2 -> fully L2-resident
// (old bx%8 mapping: 8.25 MB -> thrash). 48 KB LDS dbuf, 2-phase loop.
// ---------------------------------------------------------------------------
__device__ __forceinline__ void proj_stage(
    const __bf16* __restrict__ A, const __bf16* __restrict__ Bp,
    int k0, __bf16* As, __bf16* Bs, int tid)
{
    const int srow = tid >> 3, skc = tid & 7;          // srow 0..63
    const int ssw  = (skc ^ (srow & 7)) * 8;
#pragma unroll
    for (int it = 0; it < 2; ++it) {                   // A: 128 rows
        const int row = srow + it * 64;
        gld16(A + row * 1024 + k0 + ssw, &As[(it * 512 + tid) * 8]);
    }
    gld16(Bp + srow * 1024 + k0 + ssw, &Bs[tid * 8]);  // B: 64 rows
}

__global__ __launch_bounds__(512) void proj_gemm(
    const __bf16* __restrict__ Ain, const __bf16* __restrict__ W,
    const float* __restrict__ bias, float* __restrict__ out)
{
    __shared__ __align__(16) __bf16 As[2][128 * 64];   // [buf][m][k] swizzled
    __shared__ __align__(16) __bf16 Bs[2][64 * 64];    // [buf][n][k] swizzled
    floatx4 acc[2][2] = {};

    // XCD-rectangle remap (bijective over 512): XCD = linear%8 owns an
    // 8(bx) x 8(by) rectangle of the (16,32) tile grid.
    const int linear = blockIdx.x + (blockIdx.y << 4);
    const int xcd = linear & 7, rr = linear >> 3;      // rr 0..63
    const int bx = (xcd & 1) * 8 + (rr & 7);
    const int by = (xcd >> 1) * 8 + (rr >> 3);
    const int m0 = by * 128, n0 = bx * 64;

    const int tid = threadIdx.x, lane = tid & 63, wv = tid >> 6;   // wv 0..7
    const int quad = lane >> 4, l15 = lane & 15;
    const int wm = (wv >> 1) * 32, wn = (wv & 1) * 32; // 4 x 2 wave grid

    const __bf16* A  = Ain + (size_t)m0 * 1024;
    const __bf16* Bp = W   + (size_t)n0 * 1024;

    proj_stage(A, Bp, 0, As[0], Bs[0], tid);
    __syncthreads();

#pragma unroll 1
    for (int kk = 0; kk < 16; ++kk) {
        const int cur = kk & 1;
        if (kk < 15)
            proj_stage(A, Bp, (kk + 1) * 64, As[cur ^ 1], Bs[cur ^ 1], tid);

        const __bf16* Ab = As[cur];
        const __bf16* Bb = Bs[cur];
#pragma unroll
        for (int ks = 0; ks < 2; ++ks) {
            bf16_8 af[2], bf[2];
#pragma unroll
            for (int mt = 0; mt < 2; ++mt) {
                int r = wm + mt * 16 + l15;
                af[mt] = *(const bf16_8*)&Ab[r * 64 + (((ks * 4 + quad) ^ (r & 7)) * 8)];
            }
#pragma unroll
            for (int nt = 0; nt < 2; ++nt) {
                int r = wn + nt * 16 + l15;
                bf[nt] = *(const bf16_8*)&Bb[r * 64 + (((ks * 4 + quad) ^ (r & 7)) * 8)];
            }
#pragma unroll
            for (int mt = 0; mt < 2; ++mt)
#pragma unroll
                for (int nt = 0; nt < 2; ++nt)
                    acc[mt][nt] = MFMA16(af[mt], bf[nt], acc[mt][nt], 0, 0, 0);
        }

        if (kk < 15) {
            __asm__ __volatile__("s_waitcnt vmcnt(0)" ::: "memory");
            __syncthreads();
        }
    }

    float bv[2];
#pragma unroll
    for (int nt = 0; nt < 2; ++nt) bv[nt] = bias[n0 + wn + nt * 16 + l15];

#pragma unroll
    for (int mt = 0; mt < 2; ++mt) {
        const int m = m0 + wm + mt * 16 + quad * 4;
#pragma unroll
        for (int nt = 0; nt < 2; ++nt) {
            const int n = n0 + wn + nt * 16 + l15;
#pragma unroll
            for (int r = 0; r < 4; ++r)
                out[(size_t)(m + r) * 1024 + n] = acc[mt][nt][r] + bv[nt];
        }
    }
}

// ---------------------------------------------------------------------------
extern "C" void kernel_launch(void* const* d_in, const int* in_sizes, int n_in,
                              void* d_out, int out_size, void* d_ws, size_t ws_size,
                              hipStream_t stream)
{
    const float* x      = (const float*)d_in[0];
    const float* qkv_w  = (const float*)d_in[2];
    const float* proj_w = (const float*)d_in[3];
    const float* proj_b = (const float*)d_in[4];
    float* out = (float*)d_out;

    const size_t SZ   = 4096 * 1024;
    const size_t WQKV = 3072 * 1024;
    const size_t WPRJ = 1024 * 1024;

    __bf16* xb      = (__bf16*)d_ws;
    __bf16* qkvwb   = xb + SZ;
    __bf16* projwb  = qkvwb + WQKV;
    __bf16* q_ws    = projwb + WPRJ;
    __bf16* k_ws    = q_ws + SZ;
    __bf16* vt_ws   = k_ws + SZ;
    __bf16* attn_ws = vt_ws + SZ;

    cvt_all<<<dim3(2048), 256, 0, stream>>>(x, qkv_w, proj_w, xb, qkvwb, projwb);
    qkv_gemm  <<<dim3(24, 32), 512, 0, stream>>>(xb, qkvwb, q_ws, k_ws, vt_ws);
    attn_kernel<<<dim3(16, 32), 512, 0, stream>>>(q_ws, k_ws, vt_ws, attn_ws);
    proj_gemm <<<dim3(16, 32), 512, 0, stream>>>(attn_ws, projwb, proj_b, out);
}

// Round 13
// 178.585 us; speedup vs baseline: 1.0009x; 1.0009x over previous
//
#include <hip/hip_runtime.h>

// ---------------------------------------------------------------------------
// Attention_52424370815683: B=2, S=2048, D=1024, H=16, hd=64. f32 I/O.
// 3 kernels (cvt_all ELIMINATED -- conversion fused into consumers):
//   k1: qkv GEMM, 128x128 BK=32 dbuf 2-phase, 512 thr, 3 blocks/CU.
//       X/W REG-STAGED FROM F32 (float4 loads -> cvt -> ds_write, T14
//       issue-early/write-late inside the same 2-phase skeleton).
//       -> q[b,h,s,d], k (pre-scaled by CSCALE), vT[b,h,d,s].
//   k2: flash attention (r10/r11, banked): 512 thr / 8 waves = 4 qtiles x
//       2 keyhalves, LDS K/V dbuf per half, 32x32 swapped-QK, in-register
//       P via cvt_pk + permlane swap, split-K LDS merge. ~46.3 us.
//   k3: proj GEMM, 128x64 tile, 512 thr / 8 waves; A via gld16 (bf16),
//       W reg-staged from f32 (same fused-convert pattern).
// ---------------------------------------------------------------------------

typedef __bf16 bf16_8 __attribute__((ext_vector_type(8)));
typedef __bf16 bf16_4 __attribute__((ext_vector_type(4)));
typedef __bf16 bf16_2 __attribute__((ext_vector_type(2)));
typedef float floatx2 __attribute__((ext_vector_type(2)));
typedef float floatx4 __attribute__((ext_vector_type(4)));
typedef float floatx16 __attribute__((ext_vector_type(16)));
typedef unsigned uintx4 __attribute__((ext_vector_type(4)));

#define MFMA16 __builtin_amdgcn_mfma_f32_16x16x32_bf16
#define MFMA32 __builtin_amdgcn_mfma_f32_32x32x16_bf16
#define CSCALE 0.1803368801111204f   // hd^-0.5 * log2(e)
#define EXP2R  __builtin_amdgcn_exp2f   // bare v_exp_f32 (no OCML denorm fixup)

__device__ __forceinline__ void gld16(const __bf16* g, __bf16* l) {
    __builtin_amdgcn_global_load_lds(
        (const __attribute__((address_space(1))) void*)g,
        (__attribute__((address_space(3))) void*)l, 16, 0, 0);
}

// 8 f32 -> bf16_8 (compiler emits v_cvt_pk_bf16_f32 pairs)
__device__ __forceinline__ bf16_8 cvt8(float4 a, float4 b) {
    bf16_8 o;
    o[0] = (__bf16)a.x; o[1] = (__bf16)a.y; o[2] = (__bf16)a.z; o[3] = (__bf16)a.w;
    o[4] = (__bf16)b.x; o[5] = (__bf16)b.y; o[6] = (__bf16)b.z; o[7] = (__bf16)b.w;
    return o;
}

// single-instruction packed f32->bf16 (RNE), lo = a, hi = b
__device__ __forceinline__ unsigned cvtpk_bf16(float a, float b) {
    unsigned d;
    __asm__("v_cvt_pk_bf16_f32 %0, %1, %2" : "=v"(d) : "v"(a), "v"(b));
    return d;
}

// v_permlane32_swap_b32: after the op, a = {a_lo, b_lo}, b = {a_hi, b_hi}
// volatile: the r2/r6/r10 (passing) form -- pinned in program order.
__device__ __forceinline__ void pl32swap(unsigned& a, unsigned& b) {
    __asm__ __volatile__("v_permlane32_swap_b32 %0, %1" : "+v"(a), "+v"(b));
}

// ---------------------------------------------------------------------------
// Kernel 1: QKV GEMM. M=4096, N=3072, K=1024. grid (24,32) = 768 blocks,
// 512 threads, 8 waves (2M x 4N), 128x128 tile, BK=32, dbuf LDS (32 KB ->
// 3 blocks/CU, all 768 resident). Operands read DIRECTLY AS F32 and
// converted during staging: per step each thread loads 8 f32 per operand
// (2 float4, issued at step top -> latency hidden under MFMA phase),
// converts, ds_write_b128 after the compute phase, then barrier (same
// 1-barrier/step dbuf discipline as the r9-proven skeleton).
// Epilogues: q/k -> [b,h,s,d] (k scaled by CSCALE), v -> vT[b,h,d,s].
// ---------------------------------------------------------------------------
__global__ __launch_bounds__(512) void qkv_gemm(
    const float* __restrict__ X, const float* __restrict__ W,
    __bf16* __restrict__ q_ws, __bf16* __restrict__ k_ws, __bf16* __restrict__ vt_ws)
{
    __shared__ __align__(16) __bf16 S[2][2][128 * 32];  // [buf][A/B] 32 KB

    const int tid = threadIdx.x, lane = tid & 63, wv = tid >> 6;   // wv 0..7
    const int quad = lane >> 4, l15 = lane & 15;
    const int wm = (wv >> 2) * 64, wn = (wv & 3) * 32;  // 2 x 4 wave grid
    const int m0 = blockIdx.y * 128, n0 = blockIdx.x * 128;
    const int c = n0 >> 10;                         // 0=q 1=k 2=v (block-uniform)

    // A/B row bases (both K-major f32, stride 1024). c<2: swapped.
    const float* Abase;
    const float* Bbase;
    if (c == 2) { Abase = X + (size_t)m0 * 1024; Bbase = W + (size_t)n0 * 1024; }
    else        { Abase = W + (size_t)n0 * 1024; Bbase = X + (size_t)m0 * 1024; }

    // staging: 128 rows x 4 chunks(8 elem) = 512 chunks = 1/thread/operand.
    // physical slot skc of row srow holds logical chunk skc^(srow&3).
    const int srow = tid >> 2, skc = tid & 3;       // srow 0..127
    const int ssw  = ((skc ^ (srow & 3)) * 8);      // element offset (32B-aligned)

    float4 a0, a1, b0, b1;                          // in-flight stage regs

#define QKV_LOAD(k0)                                                           \
    {                                                                          \
        const float4* ap = (const float4*)(Abase + srow * 1024 + (k0) + ssw);  \
        const float4* bp = (const float4*)(Bbase + srow * 1024 + (k0) + ssw);  \
        a0 = ap[0]; a1 = ap[1]; b0 = bp[0]; b1 = bp[1];                        \
    }
#define QKV_WRITE(buf)                                                         \
    {                                                                          \
        *(bf16_8*)&S[buf][0][tid * 8] = cvt8(a0, a1);                          \
        *(bf16_8*)&S[buf][1][tid * 8] = cvt8(b0, b1);                          \
    }

    floatx4 acc[4][2] = {};
    QKV_LOAD(0)
    QKV_WRITE(0)
    __syncthreads();

#pragma unroll 1
    for (int kk = 0; kk < 32; ++kk) {
        const int cur = kk & 1;
        if (kk < 31) QKV_LOAD((kk + 1) * 32)        // issue early

        const __bf16* As = S[cur][0];
        const __bf16* Bs = S[cur][1];
        bf16_8 af[4], bf[2];
#pragma unroll
        for (int mt = 0; mt < 4; ++mt) {
            int r = wm + mt * 16 + l15;
            af[mt] = *(const bf16_8*)&As[r * 32 + ((quad ^ (r & 3)) * 8)];
        }
#pragma unroll
        for (int nt = 0; nt < 2; ++nt) {
            int r = wn + nt * 16 + l15;
            bf[nt] = *(const bf16_8*)&Bs[r * 32 + ((quad ^ (r & 3)) * 8)];
        }
#pragma unroll
        for (int mt = 0; mt < 4; ++mt)
#pragma unroll
            for (int nt = 0; nt < 2; ++nt)
                acc[mt][nt] = MFMA16(af[mt], bf[nt], acc[mt][nt], 0, 0, 0);

        if (kk < 31) {
            QKV_WRITE(cur ^ 1)                      // write late (post-MFMA)
            __syncthreads();                        // drains lgkm: buf ready
        }
    }

    if (c == 2) {
        // V: D rows = token, cols = feature. Pack 4 consecutive tokens -> vT.
#pragma unroll
        for (int mt = 0; mt < 4; ++mt) {
            const int mbase = m0 + wm + mt * 16 + quad * 4;   // token, 4-aligned
            const int b = mbase >> 11, s = mbase & 2047;
#pragma unroll
            for (int nt = 0; nt < 2; ++nt) {
                const int n = n0 + wn + nt * 16 + l15;
                const int h = (n >> 6) & 15, d = n & 63;
                bf16_4 pk;
#pragma unroll
                for (int r = 0; r < 4; ++r) pk[r] = (__bf16)acc[mt][nt][r];
                *(bf16_4*)&vt_ws[((size_t)(b * 16 + h) * 64 + d) * 2048 + s] = pk;
            }
        }
    } else {
        // q/k: swapped -> D rows = feature, cols = token. d-contiguous stores.
        __bf16* dst = (c == 0) ? q_ws : k_ws;
        const float scale = (c == 1) ? CSCALE : 1.0f;
#pragma unroll
        for (int mt = 0; mt < 4; ++mt) {
            const int nn = n0 + wm + mt * 16 + quad * 4;      // feature, 4-aligned
            const int h = (nn >> 6) & 15, d0 = nn & 63;
#pragma unroll
            for (int nt = 0; nt < 2; ++nt) {
                const int token = m0 + wn + nt * 16 + l15;
                const int b = token >> 11, skey = token & 2047;
                bf16_4 pk;
#pragma unroll
                for (int r = 0; r < 4; ++r) pk[r] = (__bf16)(acc[mt][nt][r] * scale);
                *(bf16_4*)&dst[((size_t)(b * 16 + h) * 2048 + skey) * 64 + d0] = pk;
            }
        }
    }
#undef QKV_LOAD
#undef QKV_WRITE
}

// ---------------------------------------------------------------------------
// Kernel 2: flash attention (r10/r11, banked). grid (16 qt, 32 bh) remapped
// (linear%8 = XCD owns 4 bh). 512 thr / 8 waves: qtile = w&3, keyhalf =
// w>>2. Each wave: 32 q x 1024 keys = 16 tiles from its half's dbuf LDS
// K/V (staged by the half's 256 threads, shared by 4 waves -> VGPR 64 ->
// high occupancy). Per tile: QK (8 MFMA32, fzero C-in), fused per-s
// {exp/pack -> permlane swap -> 2 PV MFMA}. Split-K merge via LDS overlay.
// ---------------------------------------------------------------------------
__global__ __launch_bounds__(512, 4) void attn_kernel(
    const __bf16* __restrict__ q_ws, const __bf16* __restrict__ k_ws,
    const __bf16* __restrict__ vt_ws, __bf16* __restrict__ attn_ws)
{
    __shared__ __align__(16) __bf16 Ks [2][2][64 * 64];   // [half][buf] 32 KB
    __shared__ __align__(16) __bf16 Vts[2][2][64 * 64];   // [half][buf] 32 KB

    const int tid = threadIdx.x, lane = tid & 63, w = tid >> 6;   // w 0..7
    const int l31 = lane & 31, hi = lane >> 5;
    const int qtile = w & 3, keyhalf = w >> 2;
    const int htid = tid & 255;                     // thread within half

    // XCD remap: linear = bx + 16*by in [0,512); XCD = linear%8 owns 4 bh.
    const int linear = blockIdx.x + (blockIdx.y << 4);
    const int r = linear >> 3;                      // 0..63
    const int bh = ((linear & 7) << 2) + (r & 3);
    const int qt = r >> 2;                          // 0..15
    const int q0 = qt * 128 + qtile * 32;

    const __bf16* __restrict__ qp  = q_ws  + (size_t)bh * (2048 * 64);
    const __bf16* __restrict__ kp  = k_ws  + (size_t)bh * (2048 * 64);
    const __bf16* __restrict__ vtp = vt_ws + (size_t)bh * (64 * 2048);
    const int koff = keyhalf * 1024;                // this half's key base

    // staging: loop-invariant per-lane bases
    const int srow = htid >> 3, skc = htid & 7;     // srow 0..31
    const int sw   = (skc ^ (srow & 7)) * 8;
    const __bf16* kb0 = kp  + (size_t)(koff + srow) * 64 + sw;
    const __bf16* kb1 = kp  + (size_t)(koff + srow + 32) * 64 + sw;
    const __bf16* vb0 = vtp + (size_t)srow * 2048 + koff + sw;
    const __bf16* vb1 = vtp + (size_t)(srow + 32) * 2048 + koff + sw;
    const int ldsoff = htid * 8;                    // wave-uniform + lane*16B

    // Q B-frags (4 k-steps of 16), held in registers all loop
    bf16_8 qf[4];
    {
        const int qrow = q0 + l31;
#pragma unroll
        for (int s = 0; s < 4; ++s)
            qf[s] = *(const bf16_8*)&qp[qrow * 64 + s * 16 + hi * 8];
    }

    floatx16 oacc[2] = {};                  // [d-tile] O^T accumulators
    floatx2 ls2[4] = {};                    // packed row-sum partials
    const floatx16 fzero = {};              // persistent zero C-in (hoisted)

    // prologue: stage tile 0 into buf 0
    gld16(kb0, &Ks [keyhalf][0][ldsoff]);
    gld16(kb1, &Ks [keyhalf][0][ldsoff + 2048]);
    gld16(vb0, &Vts[keyhalf][0][ldsoff]);
    gld16(vb1, &Vts[keyhalf][0][ldsoff + 2048]);
    __syncthreads();                        // drains vmcnt(0): buf0 ready

#pragma unroll 1
    for (int kt = 0; kt < 16; ++kt) {
        const int cur = kt & 1;
        // ---- issue next tile's stage FIRST (hidden under compute)
        if (kt < 15) {
            const int ko = (kt + 1) * 64;
            gld16(kb0 + ko * 64, &Ks [keyhalf][cur ^ 1][ldsoff]);
            gld16(kb1 + ko * 64, &Ks [keyhalf][cur ^ 1][ldsoff + 2048]);
            gld16(vb0 + ko,      &Vts[keyhalf][cur ^ 1][ldsoff]);
            gld16(vb1 + ko,      &Vts[keyhalf][cur ^ 1][ldsoff + 2048]);
        }
        const __bf16* Kb = Ks [keyhalf][cur];
        const __bf16* Vb = Vts[keyhalf][cur];

        // ---- S^T[64 key][32 q]: 2 key-subtiles x 4 k-steps
        floatx16 sacc[2];
        __builtin_amdgcn_s_setprio(1);
        {
            const int kc0 = hi;
            const int r0 = l31, r1 = 32 + l31;
            bf16_8 kf0 = *(const bf16_8*)&Kb[r0 * 64 + ((kc0 ^ (r0 & 7)) * 8)];
            bf16_8 kf1 = *(const bf16_8*)&Kb[r1 * 64 + ((kc0 ^ (r1 & 7)) * 8)];
            sacc[0] = MFMA32(kf0, qf[0], fzero, 0, 0, 0);
            sacc[1] = MFMA32(kf1, qf[0], fzero, 0, 0, 0);
        }
#pragma unroll
        for (int s = 1; s < 4; ++s) {
            const int kc = s * 2 + hi;
#pragma unroll
            for (int t = 0; t < 2; ++t) {
                const int row = t * 32 + l31;
                bf16_8 kf = *(const bf16_8*)&Kb[row * 64 + ((kc ^ (row & 7)) * 8)];
                sacc[t] = MFMA32(kf, qf[s], sacc[t], 0, 0, 0);
            }
        }
        __builtin_amdgcn_s_setprio(0);

        // ---- fused per-s: exp/pack quarter -> permlane swap -> 2 PV MFMAs
#pragma unroll
        for (int s = 0; s < 4; ++s) {
            const int t = s >> 1, b2 = (s & 1) * 2;
            unsigned Dw[4];                 // [jrel*2+e], j = b2+jrel
#pragma unroll
            for (int jr = 0; jr < 2; ++jr)
#pragma unroll
                for (int e = 0; e < 2; ++e) {
                    const int j = b2 + jr;
                    float pa = EXP2R(sacc[t][j * 4 + e * 2]);
                    float pb = EXP2R(sacc[t][j * 4 + e * 2 + 1]);
                    floatx2 p2; p2[0] = pa; p2[1] = pb;
                    ls2[t * 2 + e] += p2;        // v_pk_add_f32
                    Dw[jr * 2 + e] = cvtpk_bf16(pa, pb);
                }
            unsigned x0 = Dw[0], y0 = Dw[2];
            unsigned x1 = Dw[1], y1 = Dw[3];
            pl32swap(x0, y0);
            pl32swap(x1, y1);
            uintx4 uu; uu[0] = x0; uu[1] = x1; uu[2] = y0; uu[3] = y1;
            const bf16_8 pf = __builtin_bit_cast(bf16_8, uu);
            const int kc = s * 2 + hi;
            __builtin_amdgcn_s_setprio(1);
#pragma unroll
            for (int dt = 0; dt < 2; ++dt) {
                const int drow = dt * 32 + l31;
                bf16_8 vf = *(const bf16_8*)&Vb[drow * 64 + ((kc ^ (drow & 7)) * 8)];
                oacc[dt] = MFMA32(vf, pf, oacc[dt], 0, 0, 0);
            }
            __builtin_amdgcn_s_setprio(0);
        }

        // ---- single barrier per tile: stage loads drained + buf reads done
        if (kt < 15) {
            __asm__ __volatile__("s_waitcnt vmcnt(0)" ::: "memory");
            __syncthreads();
        }
    }

    // ---- this wave's row-sums over its 1024 keys (combine hi halves)
    const floatx2 lv = (ls2[0] + ls2[1]) + (ls2[2] + ls2[3]);
    const float lsum = lv[0] + lv[1];
    const float lw = lsum + __shfl_xor(lsum, 32, 64);

    // ---- split-K merge (LDS overlay on K/V buffers; all reads done)
    __syncthreads();
    floatx4* comb  = (floatx4*)&Ks[0][0][0];    // [qtile][8][64] = 32 KB exact
    float*   lcomb = (float*)&Vts[0][0][0];     // [qtile][64] = 1 KB

    if (keyhalf == 1) {
#pragma unroll
        for (int dt = 0; dt < 2; ++dt)
#pragma unroll
            for (int g = 0; g < 4; ++g) {
                floatx4 v4;
#pragma unroll
                for (int r4 = 0; r4 < 4; ++r4) v4[r4] = oacc[dt][g * 4 + r4];
                comb[((qtile * 8 + dt * 4 + g) << 6) + lane] = v4;
            }
        lcomb[(qtile << 6) + lane] = lw;
    }
    __syncthreads();
    if (keyhalf == 0) {
        // oacc C32 layout: col = q = lane&31, row d = (r&3)+8*(r>>2)+4*hi.
        const int b = bh >> 4, h = bh & 15;
        const float inv_l = 1.0f / (lw + lcomb[(qtile << 6) + lane]);
        const int token = b * 2048 + q0 + l31;
#pragma unroll
        for (int dt = 0; dt < 2; ++dt)
#pragma unroll
            for (int g = 0; g < 4; ++g) {
                const floatx4 v2 = comb[((qtile * 8 + dt * 4 + g) << 6) + lane];
                bf16_4 ok;
#pragma unroll
                for (int r4 = 0; r4 < 4; ++r4)
                    ok[r4] = (__bf16)((oacc[dt][g * 4 + r4] + v2[r4]) * inv_l);
                *(bf16_4*)&attn_ws[(size_t)token * 1024 + h * 64 + dt * 32 + g * 8 + hi * 4] = ok;
            }
    }
}

// ---------------------------------------------------------------------------
// Kernel 3: proj GEMM + bias -> f32 out. M=4096, N=1024, K=1024.
// 128x64 tiles, grid (16,32) = 512 blocks, 512 threads / 8 waves (4Mx2N).
// A (attn_ws, bf16) staged via gld16; W READ AS F32 and reg-stage-converted
// (issue-early/write-late, same dbuf discipline). 48 KB LDS, 2 blocks/CU.
// ---------------------------------------------------------------------------
__global__ __launch_bounds__(512) void proj_gemm(
    const __bf16* __restrict__ Ain, const float* __restrict__ W,
    const float* __restrict__ bias, float* __restrict__ out)
{
    __shared__ __align__(16) __bf16 As[2][128 * 64];   // [buf][m][k] swizzled
    __shared__ __align__(16) __bf16 Bs[2][64 * 64];    // [buf][n][k] swizzled
    floatx4 acc[2][2] = {};
    const int m0 = blockIdx.y * 128, n0 = blockIdx.x * 64;

    const int tid = threadIdx.x, lane = tid & 63, wv = tid >> 6;   // wv 0..7
    const int quad = lane >> 4, l15 = lane & 15;
    const int wm = (wv >> 1) * 32, wn = (wv & 1) * 32; // 4 x 2 wave grid

    const __bf16* A  = Ain + (size_t)m0 * 1024;
    const float*  Bp = W   + (size_t)n0 * 1024;

    const int srow = tid >> 3, skc = tid & 7;          // srow 0..63
    const int ssw  = (skc ^ (srow & 7)) * 8;

    float4 w0, w1;                                     // in-flight W regs

#define PROJ_STAGE_A(k0, buf)                                                  \
    {                                                                          \
        _Pragma("unroll")                                                      \
        for (int it = 0; it < 2; ++it) {               /* A: 128 rows */       \
            const int row = srow + it * 64;                                    \
            gld16(A + row * 1024 + (k0) + ssw, &As[buf][(it * 512 + tid) * 8]);\
        }                                                                      \
    }
#define PROJ_LOAD_B(k0)                                                        \
    {                                                                          \
        const float4* bp = (const float4*)(Bp + srow * 1024 + (k0) + ssw);     \
        w0 = bp[0]; w1 = bp[1];                                                \
    }

    PROJ_STAGE_A(0, 0)
    PROJ_LOAD_B(0)
    *(bf16_8*)&Bs[0][tid * 8] = cvt8(w0, w1);
    __asm__ __volatile__("s_waitcnt vmcnt(0)" ::: "memory");
    __syncthreads();

#pragma unroll 1
    for (int kk = 0; kk < 16; ++kk) {
        const int cur = kk & 1;
        if (kk < 15) {
            PROJ_STAGE_A((kk + 1) * 64, cur ^ 1)       // issue early
            PROJ_LOAD_B((kk + 1) * 64)
        }

        const __bf16* Ab = As[cur];
        const __bf16* Bb = Bs[cur];
#pragma unroll
        for (int ks = 0; ks < 2; ++ks) {
            bf16_8 af[2], bf[2];
#pragma unroll
            for (int mt = 0; mt < 2; ++mt) {
                int r = wm + mt * 16 + l15;
                af[mt] = *(const bf16_8*)&Ab[r * 64 + (((ks * 4 + quad) ^ (r & 7)) * 8)];
            }
#pragma unroll
            for (int nt = 0; nt < 2; ++nt) {
                int r = wn + nt * 16 + l15;
                bf[nt] = *(const bf16_8*)&Bb[r * 64 + (((ks * 4 + quad) ^ (r & 7)) * 8)];
            }
#pragma unroll
            for (int mt = 0; mt < 2; ++mt)
#pragma unroll
                for (int nt = 0; nt < 2; ++nt)
                    acc[mt][nt] = MFMA16(af[mt], bf[nt], acc[mt][nt], 0, 0, 0);
        }

        if (kk < 15) {
            *(bf16_8*)&Bs[cur ^ 1][tid * 8] = cvt8(w0, w1);   // write late
            __asm__ __volatile__("s_waitcnt vmcnt(0)" ::: "memory");
            __syncthreads();
        }
    }

    float bv[2];
#pragma unroll
    for (int nt = 0; nt < 2; ++nt) bv[nt] = bias[n0 + wn + nt * 16 + l15];

#pragma unroll
    for (int mt = 0; mt < 2; ++mt) {
        const int m = m0 + wm + mt * 16 + quad * 4;
#pragma unroll
        for (int nt = 0; nt < 2; ++nt) {
            const int n = n0 + wn + nt * 16 + l15;
#pragma unroll
            for (int r = 0; r < 4; ++r)
                out[(size_t)(m + r) * 1024 + n] = acc[mt][nt][r] + bv[nt];
        }
    }
#undef PROJ_STAGE_A
#undef PROJ_LOAD_B
}

// ---------------------------------------------------------------------------
extern "C" void kernel_launch(void* const* d_in, const int* in_sizes, int n_in,
                              void* d_out, int out_size, void* d_ws, size_t ws_size,
                              hipStream_t stream)
{
    const float* x      = (const float*)d_in[0];
    const float* qkv_w  = (const float*)d_in[2];
    const float* proj_w = (const float*)d_in[3];
    const float* proj_b = (const float*)d_in[4];
    float* out = (float*)d_out;

    const size_t SZ = 4096 * 1024;

    __bf16* q_ws    = (__bf16*)d_ws;
    __bf16* k_ws    = q_ws + SZ;
    __bf16* vt_ws   = k_ws + SZ;
    __bf16* attn_ws = vt_ws + SZ;

    qkv_gemm  <<<dim3(24, 32), 512, 0, stream>>>(x, qkv_w, q_ws, k_ws, vt_ws);
    attn_kernel<<<dim3(16, 32), 512, 0, stream>>>(q_ws, k_ws, vt_ws, attn_ws);
    proj_gemm <<<dim3(16, 32), 512, 0, stream>>>(attn_ws, proj_w, proj_b, out);
}